// Round 8
// baseline (1088.257 us; speedup 1.0000x reference)
//
#include <hip/hip_runtime.h>
#include <hip/hip_fp16.h>
#include <cstddef>
#include <cstdint>

typedef _Float16 f16;
typedef _Float16 f16x8 __attribute__((ext_vector_type(8)));
typedef _Float16 f16x4 __attribute__((ext_vector_type(4)));
typedef float    f32x4 __attribute__((ext_vector_type(4)));

#define BK 64   // K-tile depth (fp16 elems); 2 MFMA k-steps per tile

// async 16B global->LDS (linear LDS dest = wave-uniform base + lane*16)
__device__ __forceinline__ void gload16(const void* g, void* lds) {
  __builtin_amdgcn_global_load_lds(
      (const __attribute__((address_space(1))) unsigned int*)g,
      (__attribute__((address_space(3))) unsigned int*)lds, 16, 0, 0);
}

// Stage an [R x 64] fp16 tile via global_load_lds. LDS row r holds global
// 8-elem slot s at slot s^(r&7) (rule-21 both-sides swizzle).
template<int R>
__device__ __forceinline__ void stage_f16(f16 (*buf)[BK], const f16* __restrict__ src,
                                          int ld, int w, int lane) {
#pragma unroll
  for (int i = 0; i < R / 32; i++) {
    const int grp  = w * (R / 32) + i;          // wave-uniform
    const int r    = grp * 8 + (lane >> 3);
    const int slot = (lane & 7) ^ (r & 7);
    gload16(src + (size_t)r * ld + slot * 8, &buf[grp * 8][0]);
  }
}

// Reg-staging for f32 sources (T14 issue-early / write-late).
template<int R>
struct RegStage {
  static constexpr int NV = (R == 128) ? 8 : 4;
  float4 v[NV];
  __device__ __forceinline__ void load(const float* __restrict__ src, int ld, int tid) {
    const int r = (R == 128) ? (tid >> 1) : (tid >> 2);
    const int h = (R == 128) ? (tid & 1) * 32 : (tid & 3) * 16;
    const float* p = src + (size_t)r * ld + h;
#pragma unroll
    for (int j = 0; j < NV; j++) v[j] = ((const float4*)p)[j];
  }
  __device__ __forceinline__ void write(f16 (*buf)[BK], int tid) {
    const int r = (R == 128) ? (tid >> 1) : (tid >> 2);
    const int h = (R == 128) ? (tid & 1) * 32 : (tid & 3) * 16;
#pragma unroll
    for (int g = 0; g < NV / 2; g++) {
      const float4 a = v[g * 2], b = v[g * 2 + 1];
      f16x8 o;
      o[0] = (f16)a.x; o[1] = (f16)a.y; o[2] = (f16)a.z; o[3] = (f16)a.w;
      o[4] = (f16)b.x; o[5] = (f16)b.y; o[6] = (f16)b.z; o[7] = (f16)b.w;
      const int slot = (h / 8 + g) ^ (r & 7);
      *(f16x8*)&buf[r][slot * 8] = o;
    }
  }
};

// ---------------------------------------------------------------------------
// TN GEMM, double-buffered (R5-proven core): C = A@B^T (+bias[n]) (+relu).
// fp16 operands: global_load_lds. f32 operands: reg-stage + cvt.
// Chunked bijective XCD swizzle on (bx,by); requires nxy % 8 == 0.
// ---------------------------------------------------------------------------
template<int BMt, int BNt, typename TA, typename TB, bool BIAS, bool RELU, typename TC>
__global__ __launch_bounds__(256, 2)
void gemm_tn(const TA* __restrict__ A, int lda,
             const TB* __restrict__ B, int ldb,
             TC* __restrict__ C, int ldc,
             const float* __restrict__ bias, int K)
{
  constexpr int MF = BMt / 32;
  constexpr int NF = BNt / 32;
  __shared__ f16 As[2][BMt][BK];
  __shared__ f16 Bs[2][BNt][BK];
  const int tid  = threadIdx.x;
  const int lane = tid & 63;
  const int w    = tid >> 6;
  const int wr   = w >> 1, wc = w & 1;

  const int gx = gridDim.x, nxy = gx * gridDim.y;
  int lin = blockIdx.y * gx + blockIdx.x;
  lin = (lin & 7) * (nxy >> 3) + (lin >> 3);
  const int m0 = (lin % gx) * BMt;
  const int n0 = (lin / gx) * BNt;

  f32x4 acc[MF][NF] = {};
  RegStage<BMt> ra;   // dead when TA == f16
  RegStage<BNt> rb;   // dead when TB == f16

  auto stage_issue = [&](int buf, int k0) {
    if constexpr (sizeof(TA) == 2)
      stage_f16<BMt>(As[buf], (const f16*)A + (size_t)m0 * lda + k0, lda, w, lane);
    else
      ra.load((const float*)A + (size_t)m0 * lda + k0, lda, tid);
    if constexpr (sizeof(TB) == 2)
      stage_f16<BNt>(Bs[buf], (const f16*)B + (size_t)n0 * ldb + k0, ldb, w, lane);
    else
      rb.load((const float*)B + (size_t)n0 * ldb + k0, ldb, tid);
  };
  auto stage_write = [&](int buf) {
    if constexpr (sizeof(TA) == 4) ra.write(As[buf], tid);
    if constexpr (sizeof(TB) == 4) rb.write(Bs[buf], tid);
  };
  auto compute = [&](int buf) {
    const int fr = lane & 15, q = lane >> 4;
#pragma unroll
    for (int kk = 0; kk < 2; kk++) {
      f16x8 af[MF], bf[NF];
#pragma unroll
      for (int i = 0; i < MF; i++) {
        const int r = wr * (BMt / 2) + i * 16 + fr;
        const int slot = (kk * 4 + q) ^ (r & 7);
        af[i] = *(const f16x8*)&As[buf][r][slot * 8];
      }
#pragma unroll
      for (int j = 0; j < NF; j++) {
        const int r = wc * (BNt / 2) + j * 16 + fr;
        const int slot = (kk * 4 + q) ^ (r & 7);
        bf[j] = *(const f16x8*)&Bs[buf][r][slot * 8];
      }
#pragma unroll
      for (int i = 0; i < MF; i++)
#pragma unroll
        for (int j = 0; j < NF; j++)
          acc[i][j] = __builtin_amdgcn_mfma_f32_16x16x32_f16(af[i], bf[j], acc[i][j], 0, 0, 0);
    }
  };

  stage_issue(0, 0);
  stage_write(0);
  __syncthreads();

  const int KT = K / BK;
  for (int kt = 0; kt < KT; kt++) {
    const int cur = kt & 1, nxt = cur ^ 1;
    if (kt + 1 < KT) stage_issue(nxt, (kt + 1) * BK);
    compute(cur);
    if (kt + 1 < KT) stage_write(nxt);
    __syncthreads();
  }

  const int fr = lane & 15;
  const int rg = (lane >> 4) << 2;
#pragma unroll
  for (int i = 0; i < MF; i++) {
#pragma unroll
    for (int j = 0; j < NF; j++) {
      const int col = n0 + wc * (BNt / 2) + j * 16 + fr;
      float bv = 0.f;
      if constexpr (BIAS) bv = bias[col];
#pragma unroll
      for (int r = 0; r < 4; r++) {
        const int row = m0 + wr * (BMt / 2) + i * 16 + rg + r;
        float v = acc[i][j][r] + bv;
        if constexpr (RELU) v = fmaxf(v, 0.f);
        C[(size_t)row * ldc + col] = (TC)v;
      }
    }
  }
}

// ---------------------------------------------------------------------------
// Fused softmax + PV: out[32 x 64 tile] = relu(softmax(Srows) @ W1T^T + fcb).
// Pass 1: online max/sum over the block's 32 S-rows (f32, streaming).
// Pass 2: K-loop over t (=2048); A staged as P=exp(s-m)*inv -> fp16; B=W1T f16.
// Grid (SC/32, E/64); 4 waves, wave tile 16x32 (MF=1, NF=2).
// ---------------------------------------------------------------------------
__global__ __launch_bounds__(256, 2)
void fused_pv(const float* __restrict__ Sb, const f16* __restrict__ W1T,
              const float* __restrict__ fcb, float* __restrict__ outp)
{
  __shared__ f16 As[2][32][BK];
  __shared__ f16 Bs[2][64][BK];
  __shared__ float sm_m[32], sm_i[32];
  const int tid  = threadIdx.x;
  const int lane = tid & 63;
  const int w    = tid >> 6;
  const int wr   = w >> 1, wc = w & 1;

  const int gx = gridDim.x, nxy = gx * gridDim.y;
  int lin = blockIdx.y * gx + blockIdx.x;
  lin = (lin & 7) * (nxy >> 3) + (lin >> 3);
  const int m0 = (lin % gx) * 32;
  const int n0 = (lin / gx) * 64;

  // ---- pass 1: per-row online max/sum (8 threads per row) ----
  {
    const int r = tid >> 3, l = tid & 7;
    const float4* prow = (const float4*)(Sb + (size_t)(m0 + r) * 2048) + l;
    float m = -3.4e38f, s = 0.f;
#pragma unroll 4
    for (int i = 0; i < 64; i++) {
      const float4 v = prow[(size_t)i * 8];
      const float mv = fmaxf(fmaxf(v.x, v.y), fmaxf(v.z, v.w));
      if (mv > m) { s *= __expf(m - mv); m = mv; }
      s += __expf(v.x - m) + __expf(v.y - m) + __expf(v.z - m) + __expf(v.w - m);
    }
#pragma unroll
    for (int off = 1; off < 8; off <<= 1) {
      const float m2 = __shfl_xor(m, off), s2 = __shfl_xor(s, off);
      const float mn = fmaxf(m, m2);
      s = s * __expf(m - mn) + s2 * __expf(m2 - mn);
      m = mn;
    }
    if (l == 0) { sm_m[r] = m; sm_i[r] = 1.f / s; }
  }
  __syncthreads();

  // ---- pass 2: P @ W1T^T ----
  f32x4 acc[2] = {};

  auto stageA = [&](int buf, int k0) {
    const int ar = tid >> 3, s8 = tid & 7;
    const float* p = Sb + (size_t)(m0 + ar) * 2048 + k0 + s8 * 8;
    const float4 a = ((const float4*)p)[0];
    const float4 b = ((const float4*)p)[1];
    const float mm = sm_m[ar], iv = sm_i[ar];
    f16x8 o;
    o[0] = (f16)(__expf(a.x - mm) * iv); o[1] = (f16)(__expf(a.y - mm) * iv);
    o[2] = (f16)(__expf(a.z - mm) * iv); o[3] = (f16)(__expf(a.w - mm) * iv);
    o[4] = (f16)(__expf(b.x - mm) * iv); o[5] = (f16)(__expf(b.y - mm) * iv);
    o[6] = (f16)(__expf(b.z - mm) * iv); o[7] = (f16)(__expf(b.w - mm) * iv);
    const int slot = s8 ^ (ar & 7);
    *(f16x8*)&As[buf][ar][slot * 8] = o;
  };
  auto stageB = [&](int buf, int k0) {
    stage_f16<64>(Bs[buf], W1T + (size_t)n0 * 2048 + k0, 2048, w, lane);
  };
  auto compute = [&](int buf) {
    const int fr = lane & 15, q = lane >> 4;
#pragma unroll
    for (int kk = 0; kk < 2; kk++) {
      const int r = wr * 16 + fr;
      const int slot = (kk * 4 + q) ^ (r & 7);
      const f16x8 af = *(const f16x8*)&As[buf][r][slot * 8];
#pragma unroll
      for (int j = 0; j < 2; j++) {
        const int br = wc * 32 + j * 16 + fr;
        const int bslot = (kk * 4 + q) ^ (br & 7);
        const f16x8 bf = *(const f16x8*)&Bs[buf][br][bslot * 8];
        acc[j] = __builtin_amdgcn_mfma_f32_16x16x32_f16(af, bf, acc[j], 0, 0, 0);
      }
    }
  };

  stageB(0, 0);
  stageA(0, 0);
  __syncthreads();
  for (int kt = 0; kt < 32; kt++) {
    const int cur = kt & 1, nxt = cur ^ 1;
    if (kt + 1 < 32) { stageB(nxt, (kt + 1) * BK); stageA(nxt, (kt + 1) * BK); }
    compute(cur);
    __syncthreads();
  }

  const int fr = lane & 15;
  const int rg = (lane >> 4) << 2;
#pragma unroll
  for (int j = 0; j < 2; j++) {
    const int col = n0 + wc * 32 + j * 16 + fr;
    const float bv = fcb[col];
#pragma unroll
    for (int r = 0; r < 4; r++) {
      const int row = m0 + wr * 16 + rg + r;
      outp[(size_t)row * 512 + col] = fmaxf(acc[j][r] + bv, 0.f);
    }
  }
}

// f32 -> fp16 vector copy (8 elems/thread)
__global__ __launch_bounds__(256)
void copy_f32_f16(const float* __restrict__ in, f16* __restrict__ o)
{
  const size_t i = ((size_t)blockIdx.x * 256 + threadIdx.x) * 8;
  const float4 a = ((const float4*)(in + i))[0];
  const float4 b = ((const float4*)(in + i))[1];
  f16x8 v;
  v[0] = (f16)a.x; v[1] = (f16)a.y; v[2] = (f16)a.z; v[3] = (f16)a.w;
  v[4] = (f16)b.x; v[5] = (f16)b.y; v[6] = (f16)b.z; v[7] = (f16)b.w;
  *(f16x8*)(o + i) = v;
}

// bT[row] = dot(x1[row, :1024], bias)  (exact f32)
__global__ __launch_bounds__(256)
void bias_dot(const float* __restrict__ x1, const float* __restrict__ bias,
              float* __restrict__ bT)
{
  const int row  = blockIdx.x * 4 + (threadIdx.x >> 6);
  const int lane = threadIdx.x & 63;
  const float4* r = (const float4*)(x1 + (size_t)row * 1024);
  const float4* bb = (const float4*)bias;
  float acc = 0.f;
#pragma unroll
  for (int j = 0; j < 4; j++) {
    const float4 a = r[lane + j * 64];
    const float4 b = bb[lane + j * 64];
    acc += a.x * b.x + a.y * b.y + a.z * b.z + a.w * b.w;
  }
#pragma unroll
  for (int off = 32; off > 0; off >>= 1) acc += __shfl_xor(acc, off);
  if (lane == 0) bT[row] = acc;
}

// ---------------------------------------------------------------------------
extern "C" void kernel_launch(void* const* d_in, const int* in_sizes, int n_in,
                              void* d_out, int out_size, void* d_ws, size_t ws_size,
                              hipStream_t stream)
{
  const float* x1   = (const float*)d_in[0];
  const float* x2   = (const float*)d_in[1];
  const float* U    = (const float*)d_in[2];
  const float* bias = (const float*)d_in[3];
  const float* fcw  = (const float*)d_in[4];
  const float* fcb  = (const float*)d_in[5];
  float* out = (float*)d_out;

  const int S = 2048, D = 1024, E = 512, B = 8;
  const int SC = 1024;
  const size_t MB = 1ull << 20;
  const size_t KB64 = 64 * 1024;

  // ws: W2 4 | W1T 2 | bT 64K | Sb 8 | Uh 2 | Fh 1 = 17.06 MB (ws >= 19 proven)
  char* w = (char*)d_ws;
  f16*   W2  = (f16*)(w);
  f16*   W1T = (f16*)(w + 4 * MB);
  float* bT  = (float*)(w + 6 * MB);
  float* Sb  = (float*)(w + 6 * MB + KB64);
  f16*   Uh  = (f16*)(w + 14 * MB + KB64);
  f16*   Fh  = (f16*)(w + 16 * MB + KB64);

  // X2h_all overlays d_out (row s of out[b] aliases row s of X2h[b], 2KB each).
  // fused_pv writes chunk rows only AFTER K2 consumed them (stream-ordered).
  f16* X2h = (f16*)d_out;

  copy_f32_f16<<<dim3(B * S * D / 2048), 256, 0, stream>>>(x2, X2h);
  copy_f32_f16<<<dim3(D * D / 2048), 256, 0, stream>>>(U, Uh);
  copy_f32_f16<<<dim3(E * D / 2048), 256, 0, stream>>>(fcw, Fh);
  bias_dot<<<dim3(B * S / 4), 256, 0, stream>>>(x1, bias, bT);

  for (int b = 0; b < B; b++) {
    const float* x1b = x1 + (size_t)b * S * D;
    const f16*   X2b = X2h + (size_t)b * S * D;

    // K0: W2[t][d] = sum_e x1b[t,e] Uh[d,e]  (A f32 reg, B f16 gload) grid 256
    gemm_tn<64, 128, float, f16, false, false, f16><<<dim3(S / 64, D / 128), 256, 0, stream>>>(
        x1b, D, Uh, D, W2, D, nullptr, D);

    // W1T[e][t] = sum_d Fh[e,d] x1b[t,d]  (A f16 gload, B f32 reg) grid 256
    gemm_tn<64, 64, f16, float, false, false, f16><<<dim3(E / 64, S / 64), 256, 0, stream>>>(
        Fh, D, x1b, D, W1T, S, nullptr, D);

    for (int s0 = 0; s0 < S; s0 += SC) {
      // K2: Sb[s][t] = sum_d X2b[s0+s,d] W2[t,d] + bT[t]  grid (16,16)=256
      gemm_tn<64, 128, f16, f16, true, false, float><<<dim3(SC / 64, S / 128), 256, 0, stream>>>(
          X2b + (size_t)s0 * D, D, W2, D, Sb, S, bT + (size_t)b * S, D);
      // fused softmax+PV: out rows [s0,s0+SC) = relu(softmax(Sb) @ W1T^T + fcb)
      // grid (32,8)=256
      fused_pv<<<dim3(SC / 32, E / 64), 256, 0, stream>>>(
          Sb, W1T, fcb, out + ((size_t)b * S + s0) * E);
    }
  }
}

// Round 10
// 739.647 us; speedup vs baseline: 1.4713x; 1.4713x over previous
//
#include <hip/hip_runtime.h>
#include <hip/hip_fp16.h>
#include <cstddef>
#include <cstdint>

typedef _Float16 f16;
typedef _Float16 f16x8 __attribute__((ext_vector_type(8)));
typedef _Float16 f16x4 __attribute__((ext_vector_type(4)));
typedef float    f32x4 __attribute__((ext_vector_type(4)));

#define BK 64   // K-tile depth (fp16 elems); 2 MFMA k-steps per tile

// async 16B global->LDS (linear LDS dest = wave-uniform base + lane*16)
__device__ __forceinline__ void gload16(const void* g, void* lds) {
  __builtin_amdgcn_global_load_lds(
      (const __attribute__((address_space(1))) unsigned int*)g,
      (__attribute__((address_space(3))) unsigned int*)lds, 16, 0, 0);
}

// Stage an [R x 64] fp16 tile via global_load_lds. LDS row r holds global
// 8-elem slot s at slot s^(r&7) (rule-21 both-sides swizzle).
template<int R>
__device__ __forceinline__ void stage_f16(f16 (*buf)[BK], const f16* __restrict__ src,
                                          int ld, int w, int lane) {
#pragma unroll
  for (int i = 0; i < R / 32; i++) {
    const int grp  = w * (R / 32) + i;          // wave-uniform
    const int r    = grp * 8 + (lane >> 3);
    const int slot = (lane & 7) ^ (r & 7);
    gload16(src + (size_t)r * ld + slot * 8, &buf[grp * 8][0]);
  }
}

// Reg-staging for f32 sources (T14 issue-early / write-late).
template<int R>
struct RegStage {
  static constexpr int NV = (R == 128) ? 8 : 4;
  float4 v[NV];
  __device__ __forceinline__ void load(const float* __restrict__ src, int ld, int tid) {
    const int r = (R == 128) ? (tid >> 1) : (tid >> 2);
    const int h = (R == 128) ? (tid & 1) * 32 : (tid & 3) * 16;
    const float* p = src + (size_t)r * ld + h;
#pragma unroll
    for (int j = 0; j < NV; j++) v[j] = ((const float4*)p)[j];
  }
  __device__ __forceinline__ void write(f16 (*buf)[BK], int tid) {
    const int r = (R == 128) ? (tid >> 1) : (tid >> 2);
    const int h = (R == 128) ? (tid & 1) * 32 : (tid & 3) * 16;
#pragma unroll
    for (int g = 0; g < NV / 2; g++) {
      const float4 a = v[g * 2], b = v[g * 2 + 1];
      f16x8 o;
      o[0] = (f16)a.x; o[1] = (f16)a.y; o[2] = (f16)a.z; o[3] = (f16)a.w;
      o[4] = (f16)b.x; o[5] = (f16)b.y; o[6] = (f16)b.z; o[7] = (f16)b.w;
      const int slot = (h / 8 + g) ^ (r & 7);
      *(f16x8*)&buf[r][slot * 8] = o;
    }
  }
};

// ---------------------------------------------------------------------------
// TN GEMM, double-buffered (R5-proven core): C = A@B^T (+bias[n]) (+relu).
// fp16 operands: global_load_lds. f32 operands: reg-stage + cvt.
// Chunked bijective XCD swizzle on (bx,by); requires nxy % 8 == 0.
// ---------------------------------------------------------------------------
template<int BMt, int BNt, typename TA, typename TB, bool BIAS, bool RELU, typename TC>
__global__ __launch_bounds__(256, 2)
void gemm_tn(const TA* __restrict__ A, int lda,
             const TB* __restrict__ B, int ldb,
             TC* __restrict__ C, int ldc,
             const float* __restrict__ bias, int K)
{
  constexpr int MF = BMt / 32;
  constexpr int NF = BNt / 32;
  __shared__ f16 As[2][BMt][BK];
  __shared__ f16 Bs[2][BNt][BK];
  const int tid  = threadIdx.x;
  const int lane = tid & 63;
  const int w    = tid >> 6;
  const int wr   = w >> 1, wc = w & 1;

  const int gx = gridDim.x, nxy = gx * gridDim.y;
  int lin = blockIdx.y * gx + blockIdx.x;
  lin = (lin & 7) * (nxy >> 3) + (lin >> 3);
  const int m0 = (lin % gx) * BMt;
  const int n0 = (lin / gx) * BNt;

  f32x4 acc[MF][NF] = {};
  RegStage<BMt> ra;   // dead when TA == f16
  RegStage<BNt> rb;   // dead when TB == f16

  auto stage_issue = [&](int buf, int k0) {
    if constexpr (sizeof(TA) == 2)
      stage_f16<BMt>(As[buf], (const f16*)A + (size_t)m0 * lda + k0, lda, w, lane);
    else
      ra.load((const float*)A + (size_t)m0 * lda + k0, lda, tid);
    if constexpr (sizeof(TB) == 2)
      stage_f16<BNt>(Bs[buf], (const f16*)B + (size_t)n0 * ldb + k0, ldb, w, lane);
    else
      rb.load((const float*)B + (size_t)n0 * ldb + k0, ldb, tid);
  };
  auto stage_write = [&](int buf) {
    if constexpr (sizeof(TA) == 4) ra.write(As[buf], tid);
    if constexpr (sizeof(TB) == 4) rb.write(Bs[buf], tid);
  };
  auto compute = [&](int buf) {
    const int fr = lane & 15, q = lane >> 4;
#pragma unroll
    for (int kk = 0; kk < 2; kk++) {
      f16x8 af[MF], bf[NF];
#pragma unroll
      for (int i = 0; i < MF; i++) {
        const int r = wr * (BMt / 2) + i * 16 + fr;
        const int slot = (kk * 4 + q) ^ (r & 7);
        af[i] = *(const f16x8*)&As[buf][r][slot * 8];
      }
#pragma unroll
      for (int j = 0; j < NF; j++) {
        const int r = wc * (BNt / 2) + j * 16 + fr;
        const int slot = (kk * 4 + q) ^ (r & 7);
        bf[j] = *(const f16x8*)&Bs[buf][r][slot * 8];
      }
#pragma unroll
      for (int i = 0; i < MF; i++)
#pragma unroll
        for (int j = 0; j < NF; j++)
          acc[i][j] = __builtin_amdgcn_mfma_f32_16x16x32_f16(af[i], bf[j], acc[i][j], 0, 0, 0);
    }
  };

  stage_issue(0, 0);
  stage_write(0);
  __syncthreads();

  const int KT = K / BK;
  for (int kt = 0; kt < KT; kt++) {
    const int cur = kt & 1, nxt = cur ^ 1;
    if (kt + 1 < KT) stage_issue(nxt, (kt + 1) * BK);
    compute(cur);
    if (kt + 1 < KT) stage_write(nxt);
    __syncthreads();
  }

  const int fr = lane & 15;
  const int rg = (lane >> 4) << 2;
#pragma unroll
  for (int i = 0; i < MF; i++) {
#pragma unroll
    for (int j = 0; j < NF; j++) {
      const int col = n0 + wc * (BNt / 2) + j * 16 + fr;
      float bv = 0.f;
      if constexpr (BIAS) bv = bias[col];
#pragma unroll
      for (int r = 0; r < 4; r++) {
        const int row = m0 + wr * (BMt / 2) + i * 16 + rg + r;
        float v = acc[i][j][r] + bv;
        if constexpr (RELU) v = fmaxf(v, 0.f);
        C[(size_t)row * ldc + col] = (TC)v;
      }
    }
  }
}

// f32 -> fp16 vector copy (8 elems/thread)
__global__ __launch_bounds__(256)
void copy_f32_f16(const float* __restrict__ in, f16* __restrict__ o)
{
  const size_t i = ((size_t)blockIdx.x * 256 + threadIdx.x) * 8;
  const float4 a = ((const float4*)(in + i))[0];
  const float4 b = ((const float4*)(in + i))[1];
  f16x8 v;
  v[0] = (f16)a.x; v[1] = (f16)a.y; v[2] = (f16)a.z; v[3] = (f16)a.w;
  v[4] = (f16)b.x; v[5] = (f16)b.y; v[6] = (f16)b.z; v[7] = (f16)b.w;
  *(f16x8*)(o + i) = v;
}

// bT[row] = dot(x1[row, :1024], bias)  (exact f32)
__global__ __launch_bounds__(256)
void bias_dot(const float* __restrict__ x1, const float* __restrict__ bias,
              float* __restrict__ bT)
{
  const int row  = blockIdx.x * 4 + (threadIdx.x >> 6);
  const int lane = threadIdx.x & 63;
  const float4* r = (const float4*)(x1 + (size_t)row * 1024);
  const float4* bb = (const float4*)bias;
  float acc = 0.f;
#pragma unroll
  for (int j = 0; j < 4; j++) {
    const float4 a = r[lane + j * 64];
    const float4 b = bb[lane + j * 64];
    acc += a.x * b.x + a.y * b.y + a.z * b.z + a.w * b.w;
  }
#pragma unroll
  for (int off = 32; off > 0; off >>= 1) acc += __shfl_xor(acc, off);
  if (lane == 0) bT[row] = acc;
}

// ---------------------------------------------------------------------------
// Row softmax over 2048 f32 scores; writes P fp16 packed into first 4KB of row.
// (R5-proven: per-row ownership -> in-place is race-free.)
// ---------------------------------------------------------------------------
__global__ __launch_bounds__(256)
void softmax_rows(float* __restrict__ S)
{
  float* row = S + (size_t)blockIdx.x * 2048;
  const int t = threadIdx.x;
  const float4 v0 = ((const float4*)row)[t];
  const float4 v1 = ((const float4*)row)[t + 256];

  float m = fmaxf(fmaxf(fmaxf(v0.x, v0.y), fmaxf(v0.z, v0.w)),
                  fmaxf(fmaxf(v1.x, v1.y), fmaxf(v1.z, v1.w)));
#pragma unroll
  for (int off = 32; off > 0; off >>= 1) m = fmaxf(m, __shfl_xor(m, off));
  __shared__ float red[8];
  if ((t & 63) == 0) red[t >> 6] = m;
  __syncthreads();
  m = fmaxf(fmaxf(red[0], red[1]), fmaxf(red[2], red[3]));

  float e0 = __expf(v0.x - m), e1 = __expf(v0.y - m), e2 = __expf(v0.z - m), e3 = __expf(v0.w - m);
  float e4 = __expf(v1.x - m), e5 = __expf(v1.y - m), e6 = __expf(v1.z - m), e7 = __expf(v1.w - m);
  float s = ((e0 + e1) + (e2 + e3)) + ((e4 + e5) + (e6 + e7));
#pragma unroll
  for (int off = 32; off > 0; off >>= 1) s += __shfl_xor(s, off);
  if ((t & 63) == 0) red[4 + (t >> 6)] = s;
  __syncthreads();
  const float inv = 1.f / (red[4] + red[5] + red[6] + red[7]);

  f16x4 o0, o1;
  o0[0] = (f16)(e0 * inv); o0[1] = (f16)(e1 * inv); o0[2] = (f16)(e2 * inv); o0[3] = (f16)(e3 * inv);
  o1[0] = (f16)(e4 * inv); o1[1] = (f16)(e5 * inv); o1[2] = (f16)(e6 * inv); o1[3] = (f16)(e7 * inv);
  f16x4* orow = (f16x4*)row;
  orow[t]       = o0;
  orow[t + 256] = o1;
}

// ---------------------------------------------------------------------------
extern "C" void kernel_launch(void* const* d_in, const int* in_sizes, int n_in,
                              void* d_out, int out_size, void* d_ws, size_t ws_size,
                              hipStream_t stream)
{
  const float* x1   = (const float*)d_in[0];
  const float* x2   = (const float*)d_in[1];
  const float* U    = (const float*)d_in[2];
  const float* bias = (const float*)d_in[3];
  const float* fcw  = (const float*)d_in[4];
  const float* fcb  = (const float*)d_in[5];
  float* out = (float*)d_out;

  const int S = 2048, D = 1024, E = 512, B = 8;
  const size_t MB = 1ull << 20;
  const size_t KB64 = 64 * 1024;

  // Common layout head: W2 4MB | W1T 2MB | bT 64KB | Sb ...
  char* w = (char*)d_ws;
  f16*   W2  = (f16*)(w);
  f16*   W1T = (f16*)(w + 4 * MB);
  float* bT  = (float*)(w + 6 * MB);
  float* Sb  = (float*)(w + 6 * MB + KB64);

  // Full-batch f32 scores need 6MB+64KB+16MB = 22.07MB; adaptive (ws in [19,23) MB).
  const bool FULL = ws_size >= (22 * MB + 2 * KB64);
  const int  SC   = FULL ? 2048 : 1024;

  // Fallback-only half-precision weights (fit only when Sb is 8MB)
  f16* Uh = (f16*)(w + 14 * MB + KB64);
  f16* Fh = (f16*)(w + 16 * MB + KB64);

  // X2h_all overlays d_out exactly (row s of out[b] aliases row s of X2h[b]).
  // K4' writes out[b] only AFTER K2 of batch b consumed X2h[b] (stream-ordered).
  f16* X2h = (f16*)d_out;

  copy_f32_f16<<<dim3(B * S * D / 2048), 256, 0, stream>>>(x2, X2h);
  bias_dot<<<dim3(B * S / 4), 256, 0, stream>>>(x1, bias, bT);
  if (!FULL) {
    copy_f32_f16<<<dim3(D * D / 2048), 256, 0, stream>>>(U, Uh);
    copy_f32_f16<<<dim3(E * D / 2048), 256, 0, stream>>>(fcw, Fh);
  }

  for (int b = 0; b < B; b++) {
    const float* x1b = x1 + (size_t)b * S * D;
    const f16*   X2b = X2h + (size_t)b * S * D;

    // K0: W2[t][d] = sum_e x1b[t,e] U[d,e]   grid (32,8)=256
    if (FULL)
      gemm_tn<64, 128, float, float, false, false, f16><<<dim3(S / 64, D / 128), 256, 0, stream>>>(
          x1b, D, U, D, W2, D, nullptr, D);
    else
      gemm_tn<64, 128, float, f16, false, false, f16><<<dim3(S / 64, D / 128), 256, 0, stream>>>(
          x1b, D, Uh, D, W2, D, nullptr, D);

    // W1T[e][t] = sum_d fcw[e,d] x1b[t,d]    grid (8,32)=256
    if (FULL)
      gemm_tn<64, 64, float, float, false, false, f16><<<dim3(E / 64, S / 64), 256, 0, stream>>>(
          fcw, D, x1b, D, W1T, S, nullptr, D);
    else
      gemm_tn<64, 64, f16, float, false, false, f16><<<dim3(E / 64, S / 64), 256, 0, stream>>>(
          Fh, D, x1b, D, W1T, S, nullptr, D);

    for (int s0 = 0; s0 < S; s0 += SC) {
      // K2: Sb[s][t] = sum_d X2b[s0+s,d] W2[t,d] + bT[t]   (f32 out)
      // grid: FULL (32,16)=512 (2/CU), else (16,16)=256
      gemm_tn<64, 128, f16, f16, true, false, float><<<dim3(SC / 64, S / 128), 256, 0, stream>>>(
          X2b + (size_t)s0 * D, D, W2, D, Sb, S, bT + (size_t)b * S, D);
      // softmax -> P fp16 packed in-place (lda 2S)
      softmax_rows<<<dim3(SC), 256, 0, stream>>>(Sb);
      // K4': out rows [s0,s0+SC) = relu(P @ W1T^T + fcb)  (K=t=2048)
      gemm_tn<64, 64, f16, f16, true, true, float><<<dim3(SC / 64, E / 64), 256, 0, stream>>>(
          (const f16*)Sb, 2 * S, W1T, S, out + ((size_t)b * S + s0) * E, E, fcb, S);
    }
  }
}